// Round 4
// baseline (913.647 us; speedup 1.0000x reference)
//
#include <hip/hip_runtime.h>

typedef float f32x4 __attribute__((ext_vector_type(4)));
typedef _Float16 f16x8 __attribute__((ext_vector_type(8)));
typedef _Float16 f16x4 __attribute__((ext_vector_type(4)));

constexpr int kB = 128;     // batch
constexpr int kT = 512;     // time
constexpr int kD = 256;     // emb dim
constexpr int kG = 512;     // 4*H gates per direction
constexpr int kH = 128;     // hidden
constexpr int kK = 9;       // CRF states
constexpr int kSTART = 7;
constexpr int kSTOP = 8;
constexpr int kNB = 16;     // chains per LSTM workgroup

// gi workspace layout (written by proj, read by lstm), f16:
//   [(dir*8+group)][t][x = w*64+lane][16]   16 = q*4 + reg
// chain row r = (lane>>4)*4 + reg, unit u = w*16 + (lane&15), gate n = q*128+u.
// h workspace ALIASES the first 2048 f16 of each gi row (gi row t is dead
// once step t consumed it; t is monotone per wg, so no overlap):
//   hws row = gi + row_base, layout [x = tid][reg] f16 (tid = w*64+l).

// ---------------------------------------------------------------------------
// Kernel 1: embedding gather + input projection (f16 MFMA GEMM)
// ---------------------------------------------------------------------------
__global__ __launch_bounds__(256) void proj_kernel(
    const int* __restrict__ sentence, const int* __restrict__ lengths,
    const float* __restrict__ emb,
    const float* __restrict__ Wih_f, const float* __restrict__ b_f,
    const float* __restrict__ Wih_b, const float* __restrict__ b_b,
    _Float16* __restrict__ gi)
{
    __shared__ __align__(16) _Float16 smemA[128 * 256]; // rows=t, 512B/row
    __shared__ __align__(16) _Float16 smemW[128 * 256]; // rows=n, 512B/row

    const int bx = blockIdx.x;            // 512 row tiles (4 per batch)
    const int by = blockIdx.y;            // 8 col tiles
    const int b  = bx >> 2;
    const int t0 = (bx & 3) << 7;
    const int len = lengths[b];
    if (t0 >= len) return;                // whole tile beyond length
    const int tid = threadIdx.x;
    const int dir = by >> 2;

    // ---- stage A (gathered embedding rows, f32 -> f16, swizzled) ----
    {
        const int row = tid >> 1;
        const int kb  = (tid & 1) << 7;   // 0 or 128
        const int vocab = sentence[b * kT + t0 + row];
        const float* src = emb + (size_t)vocab * kD + kb;
        const unsigned rowbyte = row * 512;
        const unsigned sw = (row & 7) << 4;
        #pragma unroll
        for (int c = 0; c < 16; ++c) {
            float4 x0 = *(const float4*)(src + c * 8);
            float4 x1 = *(const float4*)(src + c * 8 + 4);
            f16x8 pk;
            pk[0] = (_Float16)x0.x; pk[1] = (_Float16)x0.y;
            pk[2] = (_Float16)x0.z; pk[3] = (_Float16)x0.w;
            pk[4] = (_Float16)x1.x; pk[5] = (_Float16)x1.y;
            pk[6] = (_Float16)x1.z; pk[7] = (_Float16)x1.w;
            unsigned byteoff = rowbyte + ((unsigned)((kb + c * 8) * 2) ^ sw);
            *(f16x8*)((char*)smemA + byteoff) = pk;
        }
    }
    // ---- stage W (weight rows for this col tile) ----
    {
        const int row = tid >> 1;
        const int kb  = (tid & 1) << 7;
        const int n_g = by * 128 + row;
        const int gate = n_g & (kG - 1);
        const float* src = (dir == 0 ? Wih_f : Wih_b) + (size_t)gate * kD + kb;
        const unsigned rowbyte = row * 512;
        const unsigned sw = (row & 7) << 4;
        #pragma unroll
        for (int c = 0; c < 16; ++c) {
            float4 x0 = *(const float4*)(src + c * 8);
            float4 x1 = *(const float4*)(src + c * 8 + 4);
            f16x8 pk;
            pk[0] = (_Float16)x0.x; pk[1] = (_Float16)x0.y;
            pk[2] = (_Float16)x0.z; pk[3] = (_Float16)x0.w;
            pk[4] = (_Float16)x1.x; pk[5] = (_Float16)x1.y;
            pk[6] = (_Float16)x1.z; pk[7] = (_Float16)x1.w;
            unsigned byteoff = rowbyte + ((unsigned)((kb + c * 8) * 2) ^ sw);
            *(f16x8*)((char*)smemW + byteoff) = pk;
        }
    }
    __syncthreads();

    // ---- compute: 4 waves in 2x2 grid, each 64x64 ----
    const int w    = tid >> 6;
    const int lane = tid & 63;
    const int wr = w >> 1, wc = w & 1;
    const int l15 = lane & 15, l4 = lane >> 4;

    f32x4 zero = {0.f, 0.f, 0.f, 0.f};
    f32x4 acc[4][4];
    #pragma unroll
    for (int mf = 0; mf < 4; ++mf)
        #pragma unroll
        for (int nf = 0; nf < 4; ++nf) acc[mf][nf] = zero;

    #pragma unroll
    for (int kk = 0; kk < 8; ++kk) {
        f16x8 afr[4], bfr[4];
        #pragma unroll
        for (int mf = 0; mf < 4; ++mf) {
            int row = wr * 64 + mf * 16 + l15;
            unsigned byteoff = row * 512 +
                ((unsigned)(kk * 64 + l4 * 16) ^ (unsigned)((row & 7) << 4));
            afr[mf] = *(const f16x8*)((const char*)smemA + byteoff);
        }
        #pragma unroll
        for (int nf = 0; nf < 4; ++nf) {
            int row = wc * 64 + nf * 16 + l15;
            unsigned byteoff = row * 512 +
                ((unsigned)(kk * 64 + l4 * 16) ^ (unsigned)((row & 7) << 4));
            bfr[nf] = *(const f16x8*)((const char*)smemW + byteoff);
        }
        #pragma unroll
        for (int mf = 0; mf < 4; ++mf)
            #pragma unroll
            for (int nf = 0; nf < 4; ++nf)
                acc[mf][nf] = __builtin_amdgcn_mfma_f32_16x16x32_f16(
                    afr[mf], bfr[nf], acc[mf][nf], 0, 0, 0);
    }

    // ---- epilogue: add bias, write f16 gi in lstm C-fragment layout ----
    const float* biasp = (dir == 0) ? b_f : b_b;
    const int q  = by & 3;        // gate block (n>>7)
    const int gg = b >> 4;        // chain group
    const int r  = b & 15;        // chain row within group
    _Float16* gbase = gi + ((size_t)(dir * 8 + gg) * kT) * 8192
                         + (size_t)(q * 4 + (r & 3));
    const int lanep = (r >> 2) * 16 + l15;
    #pragma unroll
    for (int nf = 0; nf < 4; ++nf) {
        int n_loc = wc * 64 + nf * 16 + l15;        // unit u (0..127)
        float bias = biasp[q * 128 + n_loc];
        _Float16* colp = gbase + (size_t)((n_loc >> 4) * 64 + lanep) * 16;
        #pragma unroll
        for (int mf = 0; mf < 4; ++mf) {
            #pragma unroll
            for (int rg = 0; rg < 4; ++rg) {
                int t = t0 + wr * 64 + mf * 16 + l4 * 4 + rg;
                colp[(size_t)t * 8192] = (_Float16)(acc[mf][nf][rg] + bias);
            }
        }
    }
}

// ---------------------------------------------------------------------------
// Kernel 2: persistent weight-stationary LSTM. 16 wgs x 512 thr.
// Counted-wait barrier (no vmcnt drain), 2-step-deep gi prefetch,
// h stored to global (aliased gi head) for the separate feats kernel.
// ---------------------------------------------------------------------------
__device__ inline float sigm(float x) {
    return __builtin_amdgcn_rcpf(1.f + __expf(-x));
}
__device__ inline float tanh_(float x) {
    float t = __expf(-2.f * fabsf(x));
    float r = (1.f - t) * __builtin_amdgcn_rcpf(1.f + t);
    return x >= 0.f ? r : -r;
}
__device__ inline void wg_barrier() {
    asm volatile("s_waitcnt lgkmcnt(0)" ::: "memory");
    __builtin_amdgcn_s_barrier();
    asm volatile("" ::: "memory");
}

// One LSTM step. TOFF: 0/1 (unroll phase, also hbuf parity). GC0/GC1: the
// statically-named prefetch registers for this phase (consumed, then reloaded
// for step s+TOFF+2).
#define LSTM_BODY(TOFF, GC0, GC1)                                             \
    do {                                                                      \
        const int tb = dir ? (smax - 1 - (s + TOFF)) : (s + TOFF);            \
        f32x4 acc[4];                                                         \
        _Pragma("unroll")                                                     \
        for (int reg = 0; reg < 4; ++reg) {                                   \
            acc[0][reg] = (float)GC0[reg];                                    \
            acc[1][reg] = (float)GC0[4 + reg];                                \
            acc[2][reg] = (float)GC1[reg];                                    \
            acc[3][reg] = (float)GC1[4 + reg];                                \
        }                                                                     \
        {   /* prefetch step s+TOFF+2 (clamped; surplus values unused) */     \
            int spf = s + TOFF + 2;                                           \
            int tpf = dir ? (smax - 1 - spf) : spf;                           \
            tpf = tpf < 0 ? 0 : (tpf > smax - 1 ? smax - 1 : tpf);            \
            GC0 = *(const f16x8*)(gip + (size_t)tpf * 8192);                  \
            GC1 = *(const f16x8*)(gip + (size_t)tpf * 8192 + 8);              \
        }                                                                     \
        _Pragma("unroll")                                                     \
        for (int kk = 0; kk < 4; ++kk)                                        \
            _Pragma("unroll")                                                 \
            for (int q = 0; q < 4; ++q)                                       \
                acc[q] = __builtin_amdgcn_mfma_f32_16x16x32_f16(              \
                    afr[kk], bfr[q][kk], acc[q], 0, 0, 0);                    \
        f16x4 hpk;                                                            \
        _Pragma("unroll")                                                     \
        for (int reg = 0; reg < 4; ++reg) {                                   \
            float gi_ = acc[0][reg], gf_ = acc[1][reg];                       \
            float gg_ = acc[2][reg], go_ = acc[3][reg];                       \
            float cn = sigm(gf_) * cst[reg] + sigm(gi_) * tanh_(gg_);         \
            float hn = sigm(go_) * tanh_(cn);                                 \
            if (tb < lenr[reg]) { cst[reg] = cn; hst[reg] = hn; }             \
            hpk[reg] = (_Float16)hst[reg];                                    \
            int rr = l4 * 4 + reg;                                            \
            unsigned bo = ((unsigned)(rr * 256 + u * 2)) ^                    \
                          (unsigned)((rr & 7) << 4);                          \
            *(_Float16*)((char*)hbuf[TOFF] + bo) = hpk[reg];                  \
        }                                                                     \
        *(f16x4*)(hrow_base + (size_t)tb * 8192) = hpk;  /* fire&forget */    \
        wg_barrier();                                                         \
        {                                                                     \
            const unsigned sw2 = (unsigned)((l15 & 7) << 4);                  \
            _Pragma("unroll")                                                 \
            for (int kk = 0; kk < 4; ++kk) {                                  \
                unsigned bo = ((unsigned)(l15 * 256 + kk * 64 + l4 * 16)) ^   \
                              sw2;                                            \
                afr[kk] = *(const f16x8*)((const char*)hbuf[TOFF] + bo);      \
            }                                                                 \
        }                                                                     \
    } while (0)

__global__ __launch_bounds__(512) void lstm_kernel(
    const _Float16* gi, _Float16* hws, const int* __restrict__ lengths,
    const float* __restrict__ Whh_f, const float* __restrict__ Whh_b)
{
    const int bid = blockIdx.x;          // 0..15
    const int dir = bid >> 3;
    const int g   = bid & 7;
    const int tid = threadIdx.x;
    const int w   = tid >> 6;
    const int l   = tid & 63;
    const int l15 = l & 15, l4 = l >> 4;

    __shared__ __align__(16) _Float16 hbuf[2][kNB * kH];   // swizzled

    // ---- Whh B-fragments, resident in VGPRs for the whole kernel ----
    const float* Whh = dir ? Whh_b : Whh_f;
    f16x8 bfr[4][4];                     // [gate q][kk]
    #pragma unroll
    for (int q = 0; q < 4; ++q) {
        #pragma unroll
        for (int kk = 0; kk < 4; ++kk) {
            int n  = q * 128 + w * 16 + l15;
            int k0 = kk * 32 + l4 * 8;
            const float* src = Whh + (size_t)n * kH + k0;
            float4 x0 = *(const float4*)(src);
            float4 x1 = *(const float4*)(src + 4);
            f16x8 v;
            v[0] = (_Float16)x0.x; v[1] = (_Float16)x0.y;
            v[2] = (_Float16)x0.z; v[3] = (_Float16)x0.w;
            v[4] = (_Float16)x1.x; v[5] = (_Float16)x1.y;
            v[6] = (_Float16)x1.z; v[7] = (_Float16)x1.w;
            bfr[q][kk] = v;
        }
    }

    // ---- per-lane chain rows and lengths ----
    int lenr[4];
    #pragma unroll
    for (int reg = 0; reg < 4; ++reg)
        lenr[reg] = lengths[g * kNB + l4 * 4 + reg];
    const int smax = lengths[g * kNB];   // sorted desc -> group max

    const int u = w * 16 + l15;          // this lane's unit column
    float cst[4] = {0.f, 0.f, 0.f, 0.f};
    float hst[4] = {0.f, 0.f, 0.f, 0.f};
    f16x8 afr[4];
    #pragma unroll
    for (int kk = 0; kk < 4; ++kk)
        #pragma unroll
        for (int j = 0; j < 8; ++j) afr[kk][j] = (_Float16)0.f;

    const _Float16* gip = gi + ((size_t)(dir * 8 + g) * kT) * 8192
                             + (size_t)(w * 64 + l) * 16;
    _Float16* hrow_base = hws + ((size_t)(dir * 8 + g) * kT) * 8192
                              + (size_t)tid * 4;

    // prologue: 2-deep prefetch (steps 0 and 1)
    int ta = dir ? (smax - 1) : 0;
    int tbx = dir ? (smax - 2) : 1;
    tbx = tbx < 0 ? 0 : (tbx > smax - 1 ? smax - 1 : tbx);
    f16x8 gcA0 = *(const f16x8*)(gip + (size_t)ta * 8192);
    f16x8 gcA1 = *(const f16x8*)(gip + (size_t)ta * 8192 + 8);
    f16x8 gcB0 = *(const f16x8*)(gip + (size_t)tbx * 8192);
    f16x8 gcB1 = *(const f16x8*)(gip + (size_t)tbx * 8192 + 8);

    for (int s = 0; s < smax; s += 2) {
        LSTM_BODY(0, gcA0, gcA1);
        if (s + 1 < smax) {
            LSTM_BODY(1, gcB0, gcB1);
        }
    }
}

// ---------------------------------------------------------------------------
// Kernel 2b: feats projection  fsum[b][t][k] = hf.Wt[:, :128] + hb.Wt[:,128:]
//            + bt.  2 threads per (b,t) (one per dir), shfl-pair reduce.
// ---------------------------------------------------------------------------
__global__ __launch_bounds__(256) void feats_kernel(
    const _Float16* __restrict__ hws, const float* __restrict__ Wt,
    const float* __restrict__ bt, float* __restrict__ fsum)
{
    __shared__ float wt_lds[kK * 256];
    __shared__ float bt_lds[kK];
    const int tid = threadIdx.x;
    for (int i = tid; i < kK * 256; i += 256) wt_lds[i] = Wt[i];
    if (tid < kK) bt_lds[tid] = bt[tid];
    __syncthreads();

    const int id  = blockIdx.x * 256 + tid;     // 131072
    const int dir = id & 1;
    const int pr  = id >> 1;                    // (b,t) pair
    const int b   = pr >> 9;
    const int t   = pr & 511;
    const int g   = b >> 4;
    const int r   = b & 15;
    const int l4r = r >> 2;
    const int reg = r & 3;

    const _Float16* rowp = hws + ((size_t)(dir * 8 + g) * kT + t) * 8192;
    float acc[kK];
    #pragma unroll
    for (int k = 0; k < kK; ++k) acc[k] = 0.f;

    #pragma unroll
    for (int w = 0; w < 8; ++w) {
        const _Float16* cp = rowp + (size_t)(w * 64 + l4r * 16) * 4;
        #pragma unroll
        for (int c = 0; c < 8; ++c) {
            f16x8 v = *(const f16x8*)(cp + c * 8);
            float h0 = (float)v[reg];
            float h1 = (float)v[4 + reg];
            int d0 = dir * 128 + w * 16 + c * 2;
            #pragma unroll
            for (int k = 0; k < kK; ++k)
                acc[k] += h0 * wt_lds[k * 256 + d0] +
                          h1 * wt_lds[k * 256 + d0 + 1];
        }
    }
    #pragma unroll
    for (int k = 0; k < kK; ++k)
        acc[k] += __shfl_xor(acc[k], 1);
    if (dir == 0) {
        float* outp = fsum + ((size_t)b * kT + t) * kK;
        #pragma unroll
        for (int k = 0; k < kK; ++k) outp[k] = acc[k] + bt_lds[k];
    }
}

// ---------------------------------------------------------------------------
// Kernel 3: CRF Viterbi via max-plus matrix reduction tree.
// ---------------------------------------------------------------------------
__global__ __launch_bounds__(512) void viterbi_kernel(
    const int* __restrict__ lengths, const float* __restrict__ trans,
    const float* __restrict__ fsumg, float* __restrict__ out)
{
    constexpr float NEG = -1e30f;
    constexpr int RA = 0;            // region A: 128 matrices
    constexpr int RB = 128 * 81;     // region B: 64 matrices
    const int b = blockIdx.x;
    const int len = lengths[b];
    const int tid = threadIdx.x;

    __shared__ float tree[(128 + 64) * 81];
    __shared__ float fsum[kT * kK];
    __shared__ float trs[81];
    __shared__ float red[16];

    if (tid < 81) trs[tid] = trans[tid];
    for (int idx = tid; idx < len * kK; idx += 512)
        fsum[idx] = fsumg[(size_t)b * kT * kK + idx];
    __syncthreads();

    // ---- fused level 0: each task = column j of R_s = M_{4s+3}..M_{4s} ----
    for (int task = tid; task < 128 * 9; task += 512) {
        int s = task / 9, j = task - s * 9;
        int tb = 4 * s;
        float uu[9];
        #pragma unroll
        for (int m = 0; m < 9; ++m)
            uu[m] = (tb < len) ? (trs[m * 9 + j] + fsum[tb * 9 + m])
                               : ((m == j) ? 0.f : NEG);
        #pragma unroll
        for (int q = 1; q < 4; ++q) {
            int t = tb + q;
            if (t < len) {
                float un[9];
                #pragma unroll
                for (int k = 0; k < 9; ++k) {
                    float v = trs[k * 9] + uu[0];
                    #pragma unroll
                    for (int m = 1; m < 9; ++m)
                        v = fmaxf(v, trs[k * 9 + m] + uu[m]);
                    un[k] = v + fsum[t * 9 + k];
                }
                #pragma unroll
                for (int k = 0; k < 9; ++k) uu[k] = un[k];
            }
        }
        #pragma unroll
        for (int k = 0; k < 9; ++k)
            tree[RA + s * 81 + k * 9 + j] = uu[k];
    }
    __syncthreads();

    // ---- tree levels: 64,32,...,1 matrices out ----
    int soff = RA, doff = RB;
    for (int np = 64; np >= 1; np >>= 1) {
        for (int idx = tid; idx < np * 81; idx += 512) {
            int s = idx / 81, o = idx - s * 81;
            int k = o / 9, j = o - k * 9;
            const float* A  = tree + soff + (2 * s + 1) * 81;
            const float* Bm = tree + soff + (2 * s) * 81;
            float v = A[k * 9] + Bm[j];
            #pragma unroll
            for (int m = 1; m < 9; ++m)
                v = fmaxf(v, A[k * 9 + m] + Bm[m * 9 + j]);
            tree[doff + s * 81 + o] = v;
        }
        int tmp = soff; soff = doff; doff = tmp;
        __syncthreads();
    }
    if (tid < kK) {
        int k = tid;
        float fv = tree[soff + k * 9 + kSTART];      // + fv0[START] = 0
        #pragma unroll
        for (int j = 0; j < 9; ++j)
            if (j != kSTART) fv = fmaxf(fv, tree[soff + k * 9 + j] - 10000.f);
        red[k] = fv + trs[kSTOP * 9 + k];
    }
    __syncthreads();
    if (tid == 0) {
        float m = red[0];
        #pragma unroll
        for (int k = 1; k < 9; ++k) m = fmaxf(m, red[k]);
        out[b] = m;
    }
}

// ---------------------------------------------------------------------------
extern "C" void kernel_launch(void* const* d_in, const int* in_sizes, int n_in,
                              void* d_out, int out_size, void* d_ws, size_t ws_size,
                              hipStream_t stream) {
    const int*   sentence = (const int*)d_in[0];
    const int*   lengths  = (const int*)d_in[1];
    const float* emb      = (const float*)d_in[2];
    const float* Wih_f    = (const float*)d_in[3];
    const float* Whh_f    = (const float*)d_in[4];
    const float* b_f      = (const float*)d_in[5];
    const float* Wih_b    = (const float*)d_in[6];
    const float* Whh_b    = (const float*)d_in[7];
    const float* b_b      = (const float*)d_in[8];
    const float* Wt       = (const float*)d_in[9];
    const float* bt       = (const float*)d_in[10];
    const float* trans    = (const float*)d_in[11];
    float* out = (float*)d_out;

    char* ws = (char*)d_ws;
    const size_t gi_bytes = (size_t)2 * kB * kT * kG * sizeof(_Float16); // 128 MiB
    _Float16* gi   = (_Float16*)ws;
    _Float16* hws  = (_Float16*)ws;                  // aliases gi row heads
    float*    fsum = (float*)(ws + gi_bytes);        // 2.25 MiB

    dim3 g1((kB * kT) / 128, 1024 / 128);
    proj_kernel<<<g1, 256, 0, stream>>>(sentence, lengths, emb,
                                        Wih_f, b_f, Wih_b, b_b, gi);
    lstm_kernel<<<16, 512, 0, stream>>>(gi, hws, lengths, Whh_f, Whh_b);
    feats_kernel<<<512, 256, 0, stream>>>(hws, Wt, bt, fsum);
    viterbi_kernel<<<128, 512, 0, stream>>>(lengths, trans, fsum, out);
}

// Round 5
// 659.408 us; speedup vs baseline: 1.3856x; 1.3856x over previous
//
#include <hip/hip_runtime.h>

typedef float f32x4 __attribute__((ext_vector_type(4)));
typedef _Float16 f16x8 __attribute__((ext_vector_type(8)));
typedef _Float16 f16x4 __attribute__((ext_vector_type(4)));

constexpr int kB = 128;     // batch
constexpr int kT = 512;     // time
constexpr int kD = 256;     // emb dim
constexpr int kG = 512;     // 4*H gates per direction
constexpr int kH = 128;     // hidden
constexpr int kK = 9;       // CRF states
constexpr int kSTART = 7;
constexpr int kSTOP = 8;
constexpr int kNB = 16;     // chains per LSTM workgroup

// gi layout, f16:  [dirg = dir*8+g][t][q(4)][u(128)][r(16)]
//   row stride (per t) = 4*128*16 = 8192 f16 = 16 KiB.
// lane (w,l4,l15) of lstm: u = w*16+l15, chains r = l4*4..l4*4+3 -> one f16x4
// at offset (q*128+u)*16 + l4*4. Proj C-subtile (one t, one q) stores exactly
// one f16x4 per lane, contiguous 512B per wave.
// hws (h output) ALIASES gi row head [0,2048): written at step t after row t
// consumed (4-step prefetch slack >> load latency).

// ---------------------------------------------------------------------------
// Kernel 1: embedding gather + input projection (f16 MFMA GEMM)
// wg = (g 0..7, tc 0..63): M = 128 rows = 8 t x 16 chains, A staged once;
// loops by = (dir,q) 0..7 restaging W, epilogue stores f16x4 per fragment.
// ---------------------------------------------------------------------------
__global__ __launch_bounds__(256) void proj_kernel(
    const int* __restrict__ sentence, const int* __restrict__ lengths,
    const float* __restrict__ emb,
    const float* __restrict__ Wih_f, const float* __restrict__ b_f,
    const float* __restrict__ Wih_b, const float* __restrict__ b_b,
    _Float16* __restrict__ gi)
{
    __shared__ __align__(16) _Float16 smemA[128 * 256]; // rows=(t,chain), 512B
    __shared__ __align__(16) _Float16 smemW[128 * 256]; // rows=gate, 512B

    const int g  = blockIdx.x >> 6;
    const int tc = blockIdx.x & 63;
    if (tc * 8 >= lengths[g * 16]) return;   // whole 8-t chunk beyond group max
    const int tid = threadIdx.x;

    // ---- stage A once: row = t_local*16 + chain ----
    {
        const int row = tid >> 1;
        const int kb  = (tid & 1) << 7;
        const int b   = g * 16 + (row & 15);
        const int t   = tc * 8 + (row >> 4);
        const int vocab = sentence[b * kT + t];
        const float* src = emb + (size_t)vocab * kD + kb;
        const unsigned rowbyte = row * 512;
        const unsigned sw = (row & 7) << 4;
        #pragma unroll
        for (int c = 0; c < 16; ++c) {
            float4 x0 = *(const float4*)(src + c * 8);
            float4 x1 = *(const float4*)(src + c * 8 + 4);
            f16x8 pk;
            pk[0] = (_Float16)x0.x; pk[1] = (_Float16)x0.y;
            pk[2] = (_Float16)x0.z; pk[3] = (_Float16)x0.w;
            pk[4] = (_Float16)x1.x; pk[5] = (_Float16)x1.y;
            pk[6] = (_Float16)x1.z; pk[7] = (_Float16)x1.w;
            unsigned byteoff = rowbyte + ((unsigned)((kb + c * 8) * 2) ^ sw);
            *(f16x8*)((char*)smemA + byteoff) = pk;
        }
    }

    const int w    = tid >> 6;
    const int lane = tid & 63;
    const int wr = w >> 1, wc = w & 1;
    const int l15 = lane & 15, l4 = lane >> 4;

    for (int by = 0; by < 8; ++by) {
        const int dir = by >> 2;
        const int q   = by & 3;
        __syncthreads();     // previous compute done (and A staged, iter 0)
        // ---- stage W rows for this (dir,q) ----
        {
            const int row = tid >> 1;
            const int kb  = (tid & 1) << 7;
            const float* src = (dir == 0 ? Wih_f : Wih_b)
                               + (size_t)(q * 128 + row) * kD + kb;
            const unsigned rowbyte = row * 512;
            const unsigned sw = (row & 7) << 4;
            #pragma unroll
            for (int c = 0; c < 16; ++c) {
                float4 x0 = *(const float4*)(src + c * 8);
                float4 x1 = *(const float4*)(src + c * 8 + 4);
                f16x8 pk;
                pk[0] = (_Float16)x0.x; pk[1] = (_Float16)x0.y;
                pk[2] = (_Float16)x0.z; pk[3] = (_Float16)x0.w;
                pk[4] = (_Float16)x1.x; pk[5] = (_Float16)x1.y;
                pk[6] = (_Float16)x1.z; pk[7] = (_Float16)x1.w;
                unsigned byteoff = rowbyte + ((unsigned)((kb + c * 8) * 2) ^ sw);
                *(f16x8*)((char*)smemW + byteoff) = pk;
            }
        }
        __syncthreads();

        f32x4 zero = {0.f, 0.f, 0.f, 0.f};
        f32x4 acc[4][4];
        #pragma unroll
        for (int mf = 0; mf < 4; ++mf)
            #pragma unroll
            for (int nf = 0; nf < 4; ++nf) acc[mf][nf] = zero;

        #pragma unroll
        for (int kk = 0; kk < 8; ++kk) {
            f16x8 afr[4], bfr[4];
            #pragma unroll
            for (int mf = 0; mf < 4; ++mf) {
                int row = wr * 64 + mf * 16 + l15;
                unsigned byteoff = row * 512 +
                    ((unsigned)(kk * 64 + l4 * 16) ^ (unsigned)((row & 7) << 4));
                afr[mf] = *(const f16x8*)((const char*)smemA + byteoff);
            }
            #pragma unroll
            for (int nf = 0; nf < 4; ++nf) {
                int row = wc * 64 + nf * 16 + l15;
                unsigned byteoff = row * 512 +
                    ((unsigned)(kk * 64 + l4 * 16) ^ (unsigned)((row & 7) << 4));
                bfr[nf] = *(const f16x8*)((const char*)smemW + byteoff);
            }
            #pragma unroll
            for (int mf = 0; mf < 4; ++mf)
                #pragma unroll
                for (int nf = 0; nf < 4; ++nf)
                    acc[mf][nf] = __builtin_amdgcn_mfma_f32_16x16x32_f16(
                        afr[mf], bfr[nf], acc[mf][nf], 0, 0, 0);
        }

        // ---- epilogue: one f16x4 (8B) store per fragment ----
        const float* biasp = (dir == 0) ? b_f : b_b;
        _Float16* dbase = gi + (size_t)(dir * 8 + g) * kT * 8192;
        #pragma unroll
        for (int nf = 0; nf < 4; ++nf) {
            int u = wc * 64 + nf * 16 + l15;
            float bias = biasp[q * 128 + u];
            #pragma unroll
            for (int mf = 0; mf < 4; ++mf) {
                int t = tc * 8 + wr * 4 + mf;
                f16x4 pk;
                #pragma unroll
                for (int rg = 0; rg < 4; ++rg)
                    pk[rg] = (_Float16)(acc[mf][nf][rg] + bias);
                *(f16x4*)(dbase + (size_t)t * 8192 + (q * 128 + u) * 16 + l4 * 4) = pk;
            }
        }
    }
}

// ---------------------------------------------------------------------------
// Kernel 2: persistent weight-stationary LSTM. 16 wgs x 512 thr.
// 4-phase branch-free main loop, 4-deep static prefetch, counted barrier,
// exp-form activation with merged rcp.
// ---------------------------------------------------------------------------
__device__ inline void wg_barrier() {
    asm volatile("s_waitcnt lgkmcnt(0)" ::: "memory");
    __builtin_amdgcn_s_barrier();
    asm volatile("" ::: "memory");
}

#define LOADSET(GP, SS)                                                       \
    do {                                                                      \
        int tt = dir ? (smax - 1 - (SS)) : (SS);                              \
        tt = tt < 0 ? 0 : (tt >= smax ? smax - 1 : tt);                       \
        const _Float16* rp = glane + (size_t)tt * 8192;                       \
        GP##0 = *(const f16x4*)(rp);                                          \
        GP##1 = *(const f16x4*)(rp + 2048);                                   \
        GP##2 = *(const f16x4*)(rp + 4096);                                   \
        GP##3 = *(const f16x4*)(rp + 6144);                                   \
    } while (0)

#define LSTM_BODY(PH, GP)                                                     \
    do {                                                                      \
        const int tb = dir ? (smax - 1 - (s + PH)) : (s + PH);                \
        f32x4 acc[4];                                                         \
        _Pragma("unroll")                                                     \
        for (int reg = 0; reg < 4; ++reg) {                                   \
            acc[0][reg] = (float)GP##0[reg];                                  \
            acc[1][reg] = (float)GP##1[reg];                                  \
            acc[2][reg] = (float)GP##2[reg];                                  \
            acc[3][reg] = (float)GP##3[reg];                                  \
        }                                                                     \
        LOADSET(GP, s + PH + 4);                                              \
        _Pragma("unroll")                                                     \
        for (int kk = 0; kk < 4; ++kk)                                        \
            _Pragma("unroll")                                                 \
            for (int q = 0; q < 4; ++q)                                       \
                acc[q] = __builtin_amdgcn_mfma_f32_16x16x32_f16(              \
                    afr[kk], bfr[q][kk], acc[q], 0, 0, 0);                    \
        f16x4 hpk;                                                            \
        _Pragma("unroll")                                                     \
        for (int reg = 0; reg < 4; ++reg) {                                   \
            float i_ = acc[0][reg], f_ = acc[1][reg];                         \
            float g_ = acc[2][reg], o_ = acc[3][reg];                         \
            g_ = fminf(fmaxf(g_, -20.f), 20.f);                               \
            float Ei = __expf(-i_), Ef = __expf(-f_);                         \
            float Eg = __expf(-2.f * g_), Eo = __expf(-o_);                   \
            float p  = (1.f - Eg) *                                           \
                __builtin_amdgcn_rcpf((1.f + Ei) * (1.f + Eg));               \
            float cn = __builtin_amdgcn_rcpf(1.f + Ef) * cst[reg] + p;        \
            float cc = fminf(fmaxf(cn, -20.f), 20.f);                         \
            float Ec = __expf(-2.f * cc);                                     \
            float hn = (1.f - Ec) *                                           \
                __builtin_amdgcn_rcpf((1.f + Eo) * (1.f + Ec));               \
            if (tb < lenr[reg]) { cst[reg] = cn; hst[reg] = hn; }             \
            hpk[reg] = (_Float16)hst[reg];                                    \
            int rr = l4 * 4 + reg;                                            \
            unsigned bo = ((unsigned)(rr * 256 + u * 2)) ^                    \
                          (unsigned)((rr & 7) << 4);                          \
            *(_Float16*)((char*)hbuf[(PH) & 1] + bo) = hpk[reg];              \
        }                                                                     \
        *(f16x4*)(hrow_base + (size_t)tb * 8192) = hpk;                       \
        wg_barrier();                                                         \
        {                                                                     \
            const unsigned sw2 = (unsigned)((l15 & 7) << 4);                  \
            _Pragma("unroll")                                                 \
            for (int kk = 0; kk < 4; ++kk) {                                  \
                unsigned bo = ((unsigned)(l15 * 256 + kk * 64 + l4 * 16)) ^   \
                              sw2;                                            \
                afr[kk] = *(const f16x8*)((const char*)hbuf[(PH) & 1] + bo);  \
            }                                                                 \
        }                                                                     \
    } while (0)

__global__ __launch_bounds__(512) void lstm_kernel(
    const _Float16* gi, _Float16* hws, const int* __restrict__ lengths,
    const float* __restrict__ Whh_f, const float* __restrict__ Whh_b)
{
    const int bid = blockIdx.x;          // 0..15
    const int dir = bid >> 3;
    const int g   = bid & 7;
    const int tid = threadIdx.x;
    const int w   = tid >> 6;
    const int l   = tid & 63;
    const int l15 = l & 15, l4 = l >> 4;

    __shared__ __align__(16) _Float16 hbuf[2][kNB * kH];

    // ---- Whh B-fragments resident in VGPRs ----
    const float* Whh = dir ? Whh_b : Whh_f;
    f16x8 bfr[4][4];
    #pragma unroll
    for (int q = 0; q < 4; ++q) {
        #pragma unroll
        for (int kk = 0; kk < 4; ++kk) {
            int n  = q * 128 + w * 16 + l15;
            int k0 = kk * 32 + l4 * 8;
            const float* src = Whh + (size_t)n * kH + k0;
            float4 x0 = *(const float4*)(src);
            float4 x1 = *(const float4*)(src + 4);
            f16x8 v;
            v[0] = (_Float16)x0.x; v[1] = (_Float16)x0.y;
            v[2] = (_Float16)x0.z; v[3] = (_Float16)x0.w;
            v[4] = (_Float16)x1.x; v[5] = (_Float16)x1.y;
            v[6] = (_Float16)x1.z; v[7] = (_Float16)x1.w;
            bfr[q][kk] = v;
        }
    }

    int lenr[4];
    #pragma unroll
    for (int reg = 0; reg < 4; ++reg)
        lenr[reg] = lengths[g * kNB + l4 * 4 + reg];
    const int smax = lengths[g * kNB];

    const int u = w * 16 + l15;
    float cst[4] = {0.f, 0.f, 0.f, 0.f};
    float hst[4] = {0.f, 0.f, 0.f, 0.f};
    f16x8 afr[4];
    #pragma unroll
    for (int kk = 0; kk < 4; ++kk)
        #pragma unroll
        for (int j = 0; j < 8; ++j) afr[kk][j] = (_Float16)0.f;

    const _Float16* glane = gi + (size_t)(dir * 8 + g) * kT * 8192
                               + (size_t)(u * 16 + l4 * 4);
    _Float16* hrow_base = hws + (size_t)(dir * 8 + g) * kT * 8192
                              + (size_t)tid * 4;

    f16x4 gA0, gA1, gA2, gA3, gB0, gB1, gB2, gB3;
    f16x4 gC0, gC1, gC2, gC3, gD0, gD1, gD2, gD3;
    {
        int s = 0;
        LOADSET(gA, 0); LOADSET(gB, 1); LOADSET(gC, 2); LOADSET(gD, 3);
        (void)s;
    }

    int s = 0;
    for (; s + 4 <= smax; s += 4) {
        LSTM_BODY(0, gA);
        LSTM_BODY(1, gB);
        LSTM_BODY(2, gC);
        LSTM_BODY(3, gD);
    }
    // ---- tail (<=3 steps) ----
    for (; s < smax; ++s) {
        const int tb = dir ? (smax - 1 - s) : s;
        const _Float16* rp = glane + (size_t)tb * 8192;
        f16x4 t0 = *(const f16x4*)(rp);
        f16x4 t1 = *(const f16x4*)(rp + 2048);
        f16x4 t2 = *(const f16x4*)(rp + 4096);
        f16x4 t3 = *(const f16x4*)(rp + 6144);
        f32x4 acc[4];
        #pragma unroll
        for (int reg = 0; reg < 4; ++reg) {
            acc[0][reg] = (float)t0[reg]; acc[1][reg] = (float)t1[reg];
            acc[2][reg] = (float)t2[reg]; acc[3][reg] = (float)t3[reg];
        }
        #pragma unroll
        for (int kk = 0; kk < 4; ++kk)
            #pragma unroll
            for (int q = 0; q < 4; ++q)
                acc[q] = __builtin_amdgcn_mfma_f32_16x16x32_f16(
                    afr[kk], bfr[q][kk], acc[q], 0, 0, 0);
        f16x4 hpk;
        #pragma unroll
        for (int reg = 0; reg < 4; ++reg) {
            float i_ = acc[0][reg], f_ = acc[1][reg];
            float g_ = acc[2][reg], o_ = acc[3][reg];
            g_ = fminf(fmaxf(g_, -20.f), 20.f);
            float Ei = __expf(-i_), Ef = __expf(-f_);
            float Eg = __expf(-2.f * g_), Eo = __expf(-o_);
            float p  = (1.f - Eg) *
                __builtin_amdgcn_rcpf((1.f + Ei) * (1.f + Eg));
            float cn = __builtin_amdgcn_rcpf(1.f + Ef) * cst[reg] + p;
            float cc = fminf(fmaxf(cn, -20.f), 20.f);
            float Ec = __expf(-2.f * cc);
            float hn = (1.f - Ec) *
                __builtin_amdgcn_rcpf((1.f + Eo) * (1.f + Ec));
            if (tb < lenr[reg]) { cst[reg] = cn; hst[reg] = hn; }
            hpk[reg] = (_Float16)hst[reg];
            int rr = l4 * 4 + reg;
            unsigned bo = ((unsigned)(rr * 256 + u * 2)) ^
                          (unsigned)((rr & 7) << 4);
            *(_Float16*)((char*)hbuf[s & 1] + bo) = hpk[reg];
        }
        *(f16x4*)(hrow_base + (size_t)tb * 8192) = hpk;
        wg_barrier();
        {
            const unsigned sw2 = (unsigned)((l15 & 7) << 4);
            #pragma unroll
            for (int kk = 0; kk < 4; ++kk) {
                unsigned bo = ((unsigned)(l15 * 256 + kk * 64 + l4 * 16)) ^ sw2;
                afr[kk] = *(const f16x8*)((const char*)hbuf[s & 1] + bo);
            }
        }
    }
}

// ---------------------------------------------------------------------------
// Kernel 2b: feats. wg per (g, t): stage both dir h-rows (4KB each) + Wt,
// 144 threads compute fsum[b][t][k] = hf.Wt[:, :128] + hb.Wt[:, 128:] + bt.
// ---------------------------------------------------------------------------
__global__ __launch_bounds__(256) void feats_kernel(
    const _Float16* __restrict__ hws, const float* __restrict__ Wt,
    const float* __restrict__ bt, float* __restrict__ fsum)
{
    __shared__ _Float16 hf[2048], hb[2048];
    __shared__ float wts[kK * 256];
    __shared__ float bts[kK];
    const int g = blockIdx.x >> 9;
    const int t = blockIdx.x & 511;
    const int tid = threadIdx.x;

    *(f16x8*)&hf[tid * 8] =
        *(const f16x8*)(hws + ((size_t)g * kT + t) * 8192 + tid * 8);
    *(f16x8*)&hb[tid * 8] =
        *(const f16x8*)(hws + ((size_t)(8 + g) * kT + t) * 8192 + tid * 8);
    for (int i = tid; i < kK * 256; i += 256) wts[i] = Wt[i];
    if (tid < kK) bts[tid] = bt[tid];
    __syncthreads();

    if (tid < 144) {
        const int k = tid >> 4;      // 0..8
        const int r = tid & 15;      // chain in group
        float acc = bts[k];
        #pragma unroll 8
        for (int uu = 0; uu < kH; ++uu) {
            int idx = (uu >> 4) * 256 + (r >> 2) * 64 + (uu & 15) * 4 + (r & 3);
            acc += (float)hf[idx] * wts[k * 256 + uu] +
                   (float)hb[idx] * wts[k * 256 + 128 + uu];
        }
        fsum[((size_t)(g * 16 + r) * kT + t) * kK + k] = acc;
    }
}

// ---------------------------------------------------------------------------
// Kernel 3: CRF Viterbi via max-plus matrix reduction tree.
// ---------------------------------------------------------------------------
__global__ __launch_bounds__(512) void viterbi_kernel(
    const int* __restrict__ lengths, const float* __restrict__ trans,
    const float* __restrict__ fsumg, float* __restrict__ out)
{
    constexpr float NEG = -1e30f;
    constexpr int RA = 0;
    constexpr int RB = 128 * 81;
    const int b = blockIdx.x;
    const int len = lengths[b];
    const int tid = threadIdx.x;

    __shared__ float tree[(128 + 64) * 81];
    __shared__ float fsum[kT * kK];
    __shared__ float trs[81];
    __shared__ float red[16];

    if (tid < 81) trs[tid] = trans[tid];
    for (int idx = tid; idx < len * kK; idx += 512)
        fsum[idx] = fsumg[(size_t)b * kT * kK + idx];
    __syncthreads();

    for (int task = tid; task < 128 * 9; task += 512) {
        int s = task / 9, j = task - s * 9;
        int tb = 4 * s;
        float uu[9];
        #pragma unroll
        for (int m = 0; m < 9; ++m)
            uu[m] = (tb < len) ? (trs[m * 9 + j] + fsum[tb * 9 + m])
                               : ((m == j) ? 0.f : NEG);
        #pragma unroll
        for (int q = 1; q < 4; ++q) {
            int t = tb + q;
            if (t < len) {
                float un[9];
                #pragma unroll
                for (int k = 0; k < 9; ++k) {
                    float v = trs[k * 9] + uu[0];
                    #pragma unroll
                    for (int m = 1; m < 9; ++m)
                        v = fmaxf(v, trs[k * 9 + m] + uu[m]);
                    un[k] = v + fsum[t * 9 + k];
                }
                #pragma unroll
                for (int k = 0; k < 9; ++k) uu[k] = un[k];
            }
        }
        #pragma unroll
        for (int k = 0; k < 9; ++k)
            tree[RA + s * 81 + k * 9 + j] = uu[k];
    }
    __syncthreads();

    int soff = RA, doff = RB;
    for (int np = 64; np >= 1; np >>= 1) {
        for (int idx = tid; idx < np * 81; idx += 512) {
            int s = idx / 81, o = idx - s * 81;
            int k = o / 9, j = o - k * 9;
            const float* A  = tree + soff + (2 * s + 1) * 81;
            const float* Bm = tree + soff + (2 * s) * 81;
            float v = A[k * 9] + Bm[j];
            #pragma unroll
            for (int m = 1; m < 9; ++m)
                v = fmaxf(v, A[k * 9 + m] + Bm[m * 9 + j]);
            tree[doff + s * 81 + o] = v;
        }
        int tmp = soff; soff = doff; doff = tmp;
        __syncthreads();
    }
    if (tid < kK) {
        int k = tid;
        float fv = tree[soff + k * 9 + kSTART];
        #pragma unroll
        for (int j = 0; j < 9; ++j)
            if (j != kSTART) fv = fmaxf(fv, tree[soff + k * 9 + j] - 10000.f);
        red[k] = fv + trs[kSTOP * 9 + k];
    }
    __syncthreads();
    if (tid == 0) {
        float m = red[0];
        #pragma unroll
        for (int k = 1; k < 9; ++k) m = fmaxf(m, red[k]);
        out[b] = m;
    }
}

// ---------------------------------------------------------------------------
extern "C" void kernel_launch(void* const* d_in, const int* in_sizes, int n_in,
                              void* d_out, int out_size, void* d_ws, size_t ws_size,
                              hipStream_t stream) {
    const int*   sentence = (const int*)d_in[0];
    const int*   lengths  = (const int*)d_in[1];
    const float* emb      = (const float*)d_in[2];
    const float* Wih_f    = (const float*)d_in[3];
    const float* Whh_f    = (const float*)d_in[4];
    const float* b_f      = (const float*)d_in[5];
    const float* Wih_b    = (const float*)d_in[6];
    const float* Whh_b    = (const float*)d_in[7];
    const float* b_b      = (const float*)d_in[8];
    const float* Wt       = (const float*)d_in[9];
    const float* bt       = (const float*)d_in[10];
    const float* trans    = (const float*)d_in[11];
    float* out = (float*)d_out;

    char* ws = (char*)d_ws;
    const size_t gi_bytes = (size_t)2 * kB * kT * kG * sizeof(_Float16); // 128 MiB
    _Float16* gi   = (_Float16*)ws;
    _Float16* hws  = (_Float16*)ws;                  // aliases gi row heads
    float*    fsum = (float*)(ws + gi_bytes);        // 2.25 MiB

    proj_kernel<<<512, 256, 0, stream>>>(sentence, lengths, emb,
                                         Wih_f, b_f, Wih_b, b_b, gi);
    lstm_kernel<<<16, 512, 0, stream>>>(gi, hws, lengths, Whh_f, Whh_b);
    feats_kernel<<<4096, 256, 0, stream>>>(hws, Wt, bt, fsum);
    viterbi_kernel<<<128, 512, 0, stream>>>(lengths, trans, fsum, out);
}